// Round 1
// 1032.717 us; speedup vs baseline: 1.1453x; 1.1453x over previous
//
#include <hip/hip_runtime.h>

// RecurrentModel: 2-layer GRU stack. Persistent-weight team design.
// 32 teams x 8 blocks. Team = (batch-group of 64) x (time-chunk of 32).
// Block j of a team owns hidden cols [32j,32j+32) of BOTH layers; its weight
// row-slices live in LDS for the whole kernel. Per step, teams exchange
// h-state slices via L2-resident d_ws buffers + device-scope atomic flags.
// R1: per-team flag padding (512B stride), relaxed spin + single acquire
//     fence, s_sleep(2) — kills device-wide RMW serialization on the two
//     shared flag cache lines.
#define T_    256
#define B_    256
#define IN_   64
#define HID_  512
#define LS_   256
#define G3_   768
#define TBS_  32     // timesteps per team
#define MBT_  64     // batch rows per team
#define WP_   264    // LDS weight row pitch in shorts (528B: 16B-aligned, 2-way-bank free)
#define FSTRIDE_ 128 // ints per team flag region (512 B); flag1 at +64 ints

typedef short bf16x8v __attribute__((ext_vector_type(8)));
typedef float f32x4  __attribute__((ext_vector_type(4)));

#define MFMA_B16(A, B, C) __builtin_amdgcn_mfma_f32_16x16x32_bf16(A, B, C, 0, 0, 0)

__device__ __forceinline__ unsigned short f2bf(float f) {
  union { float f; unsigned u; } v; v.f = f;
  unsigned r = v.u + 0x7fffu + ((v.u >> 16) & 1u);   // RNE
  return (unsigned short)(r >> 16);
}
__device__ __forceinline__ float sigm(float x) { return 1.0f / (1.0f + __expf(-x)); }
__device__ __forceinline__ float tanh_f(float x) {
  x = fminf(fmaxf(x, -15.0f), 15.0f);
  float e = __expf(-2.0f * x);
  return (1.0f - e) / (1.0f + e);
}

// ---------------- prep 1: bf16 weight conversion + reset sniff + flag zero ----
__global__ void prep_conv(const float* __restrict__ whh0, const float* __restrict__ wih1,
                          const float* __restrict__ whh1, const unsigned char* __restrict__ rst,
                          unsigned short* __restrict__ dst, int* __restrict__ flagp,
                          int* __restrict__ flags) {
  const int idx = blockIdx.x * blockDim.x + threadIdx.x;
  const int N1 = G3_ * LS_;
  if (idx < 3 * N1) {
    float v;
    if (idx < N1)            v = whh0[idx];
    else if (idx < 2 * N1)   v = wih1[idx - N1];
    else                     v = whh1[idx - 2 * N1];
    dst[idx] = f2bf(v);
  }
  if (blockIdx.x == 1 && threadIdx.x < 64) {
    // zero per-team padded flags: flag0 at team*FSTRIDE_, flag1 at +64
    int tm = threadIdx.x & 31;
    flags[tm * FSTRIDE_ + ((threadIdx.x & 32) ? 64 : 0)] = 0;
  }
  if (blockIdx.x == 0) {
    __shared__ int f;
    if (threadIdx.x == 0) f = 0;
    __syncthreads();
    int any = 0;
    for (int i = 0; i < 8; ++i) {
      int off = threadIdx.x * 8 + i;
      if ((off & 3) && rst[off]) any = 1;
    }
    if (any) atomicOr(&f, 1);
    __syncthreads();
    if (threadIdx.x == 0) *flagp = f;   // 1 => byte-packed reset
  }
}

// ---------------- prep 2: fused embed W_c = w_ih0 @ W_lin, b_c --------------
__global__ void prep_wc(const float* __restrict__ W_lin, const float* __restrict__ b_lin,
                        const float* __restrict__ w_ih0, const float* __restrict__ b_ih0,
                        unsigned short* __restrict__ wc, float* __restrict__ bc) {
  const int n = blockIdx.x;
  const int i = threadIdx.x;
  const float* wrow = w_ih0 + (size_t)n * HID_;
  float acc = 0.f;
  for (int h = 0; h < HID_; ++h) acc += wrow[h] * W_lin[h * IN_ + i];
  wc[n * IN_ + i] = f2bf(acc);
  float pb = 0.f;
  for (int h = i; h < HID_; h += 64) pb += wrow[h] * b_lin[h];
  __shared__ float red[64];
  red[i] = pb;
  __syncthreads();
  if (i == 0) {
    float s = 0.f;
    for (int k = 0; k < 64; ++k) s += red[k];
    bc[n] = s + b_ih0[n];
  }
}

// ---------------- main: persistent-weight recurrent kernel ------------------
__global__ __launch_bounds__(512, 2) void gru_main(
    const float* __restrict__ obs, const unsigned char* __restrict__ rst,
    const float* __restrict__ h_init,
    const unsigned short* __restrict__ wc,     // [768][64] bf16 (global, L2-hot)
    const unsigned short* __restrict__ whh0g,  // [768][256] bf16
    const unsigned short* __restrict__ wih1g, const unsigned short* __restrict__ whh1g,
    const float* __restrict__ bcp, const float* __restrict__ bhh0,
    const float* __restrict__ bih1, const float* __restrict__ bhh1,
    const int* __restrict__ flagp, int* __restrict__ flag0, int* __restrict__ flag1,
    unsigned short* __restrict__ hx0, unsigned short* __restrict__ hx1,
    float* __restrict__ out) {

  // Weight slices, persistent all-kernel: [whh0 | wih1 | whh1], 96 rows x 264 pitch
  __shared__ __align__(16) unsigned short wlds[3 * 96 * WP_];   // 152064 B
  __shared__ int s_sm[64];
  __shared__ int s_start_sh;

  const int tid  = threadIdx.x;
  const int lane = tid & 63;
  const int wave = tid >> 6;
  const int l15  = lane & 15;
  const int quad = lane >> 4;
  const int mt   = wave & 3;            // m16 tile (batch rows mt*16..+16)
  const int c16  = (wave >> 2) * 16;    // col-16 half of the 32-col slice

  // block -> (team, slice j); bx&7 ~ XCD heuristic (correctness-independent)
  const int x  = blockIdx.x;
  const int cx = x & 7, m8 = x >> 3;
  const int j  = m8 & 7;                // col-slice 0..7
  const int team = cx * 4 + (m8 >> 3);  // 0..31 (4 teams per XCD)
  const int bg = team & 3, tc = team >> 2;
  const int b0 = bg * MBT_, t0 = tc * TBS_;

  // per-team private flag words (512-B stride kills cross-team line contention)
  int* f0 = flag0 + team * FSTRIDE_;
  int* f1 = flag1 + team * FSTRIDE_;

  const int flag = *flagp;
#define RVAL(i) (rst[flag ? (i) : ((i) << 2)] != 0)

  // ---- stage weight slices into LDS (once) ----
#pragma unroll
  for (int q = 0; q < 3; ++q) {
    const unsigned short* src = (q == 0) ? whh0g : (q == 1) ? wih1g : whh1g;
    for (int cid = tid; cid < 96 * 32; cid += 512) {      // 16B chunks
      int lr = cid >> 5, off8 = (cid & 31) * 8;           // row, short-offset
      int g = lr >> 5, cc = lr & 31;
      int grow = (g << 8) + (j << 5) + cc;                // g*256 + j*32 + cc
      *(f32x4*)&wlds[(q * 96 + lr) * WP_ + off8] =
          *(const f32x4*)&src[(size_t)grow * 256 + off8];
    }
  }

  // ---- per-lane biases (cols this wave computes) ----
  const int colg = j * 32 + c16 + l15;   // 0..255 within layer
  const float b0r = bcp[colg] + bhh0[colg];
  const float b0z = bcp[256 + colg] + bhh0[256 + colg];
  const float b0i = bcp[512 + colg];
  const float b0h = bhh0[512 + colg];
  const float b1r = bih1[colg] + bhh1[colg];
  const float b1z = bih1[256 + colg] + bhh1[256 + colg];
  const float b1i = bih1[512 + colg];
  const float b1h = bhh1[512 + colg];

  // ---- team-uniform safe start (last reset <= t0 across the 64 batch rows) ----
  if (tid < 64) {
    int s = 0;
    for (int tt = t0; tt >= 1; --tt) {
      if (RVAL(tt * B_ + b0 + tid)) { s = tt; break; }
    }
    s_sm[tid] = s;
  }
  __syncthreads();
  if (tid == 0) {
    int s = s_sm[0];
    for (int k = 1; k < 64; ++k) s = s < s_sm[k] ? s : s_sm[k];
    s_start_sh = s;
  }
  __syncthreads();
  const int s_start = s_start_sh;   // identical across the 8 sibling blocks

  // ---- init A-fragments (full h rows mt*16+l15) and fp32 carries ----
  bf16x8v h0A[8], h1A[8];
  const bf16x8v z8 = {0, 0, 0, 0, 0, 0, 0, 0};
#pragma unroll
  for (int kc = 0; kc < 8; ++kc) { h0A[kc] = z8; h1A[kc] = z8; }
  float h0v[4] = {0.f, 0.f, 0.f, 0.f}, h1v[4] = {0.f, 0.f, 0.f, 0.f};
  if (s_start == 0) {
    const float* hrow = h_init + (size_t)(b0 + mt * 16 + l15) * HID_;
#pragma unroll
    for (int kc = 0; kc < 8; ++kc) {
      f32x4 u0 = *(const f32x4*)(hrow + kc * 32 + quad * 8);
      f32x4 u1 = *(const f32x4*)(hrow + kc * 32 + quad * 8 + 4);
      f32x4 v0 = *(const f32x4*)(hrow + 256 + kc * 32 + quad * 8);
      f32x4 v1 = *(const f32x4*)(hrow + 256 + kc * 32 + quad * 8 + 4);
      bf16x8v a, b;
#pragma unroll
      for (int e = 0; e < 4; ++e) {
        a[e] = (short)f2bf(u0[e]); a[4 + e] = (short)f2bf(u1[e]);
        b[e] = (short)f2bf(v0[e]); b[4 + e] = (short)f2bf(v1[e]);
      }
      h0A[kc] = a; h1A[kc] = b;
    }
#pragma unroll
    for (int r = 0; r < 4; ++r) {
      const int m = mt * 16 + quad * 4 + r;
      h0v[r] = h_init[(size_t)(b0 + m) * HID_ + colg];
      h1v[r] = h_init[(size_t)(b0 + m) * HID_ + 256 + colg];
    }
  }

  const unsigned short* wR0 = &wlds[(0 * 96 + 0 * 32 + c16 + l15) * WP_];
  const unsigned short* wZ0 = &wlds[(0 * 96 + 1 * 32 + c16 + l15) * WP_];
  const unsigned short* wN0 = &wlds[(0 * 96 + 2 * 32 + c16 + l15) * WP_];
  const unsigned short* iR1 = &wlds[(1 * 96 + 0 * 32 + c16 + l15) * WP_];
  const unsigned short* iZ1 = &wlds[(1 * 96 + 1 * 32 + c16 + l15) * WP_];
  const unsigned short* iN1 = &wlds[(1 * 96 + 2 * 32 + c16 + l15) * WP_];
  const unsigned short* hR1 = &wlds[(2 * 96 + 0 * 32 + c16 + l15) * WP_];
  const unsigned short* hZ1 = &wlds[(2 * 96 + 1 * 32 + c16 + l15) * WP_];
  const unsigned short* hN1 = &wlds[(2 * 96 + 2 * 32 + c16 + l15) * WP_];

  for (int t = s_start; t < t0 + TBS_; ++t) {
    const int  kk = t - s_start + 1;          // 1-based team step counter
    const bool wr = (t >= t0);
    const bool rs0 = RVAL(t * B_ + b0 + mt * 16 + l15);   // A-row mask
    bool rse[4];
#pragma unroll
    for (int r = 0; r < 4; ++r) rse[r] = RVAL(t * B_ + b0 + mt * 16 + quad * 4 + r);

    // ============ layer 0 ============
    f32x4 ar = {0.f, 0.f, 0.f, 0.f}, az = ar, ani = ar, anh = ar;
    // input side: obs @ W_c^T (K=64)
    {
      const float* po = obs + ((size_t)t * B_ + b0 + mt * 16 + l15) * IN_;
#pragma unroll
      for (int kc = 0; kc < 2; ++kc) {
        f32x4 u0 = __builtin_nontemporal_load((const f32x4*)(po + kc * 32 + quad * 8));
        f32x4 u1 = __builtin_nontemporal_load((const f32x4*)(po + kc * 32 + quad * 8 + 4));
        bf16x8v oA;
#pragma unroll
        for (int e = 0; e < 4; ++e) { oA[e] = (short)f2bf(u0[e]); oA[4 + e] = (short)f2bf(u1[e]); }
        const size_t wo = (size_t)colg * 64 + kc * 32 + quad * 8;
        bf16x8v br = *(const bf16x8v*)&wc[wo];
        bf16x8v bz = *(const bf16x8v*)&wc[wo + (size_t)256 * 64];
        bf16x8v bn = *(const bf16x8v*)&wc[wo + (size_t)512 * 64];
        ar  = MFMA_B16(oA, br, ar);
        az  = MFMA_B16(oA, bz, az);
        ani = MFMA_B16(oA, bn, ani);
      }
    }
    // h side: (mask*h0[t-1]) @ whh0^T (K=256, LDS weights)
#pragma unroll
    for (int kc = 0; kc < 8; ++kc) {
      bf16x8v am = rs0 ? z8 : h0A[kc];
      const int o = kc * 32 + quad * 8;
      ar  = MFMA_B16(am, *(const bf16x8v*)&wR0[o], ar);
      az  = MFMA_B16(am, *(const bf16x8v*)&wZ0[o], az);
      anh = MFMA_B16(am, *(const bf16x8v*)&wN0[o], anh);
    }
    // epilogue 0: fp32 carry, publish slice, out
    {
      unsigned short* hw = hx0 + ((size_t)team * 2 + (kk & 1)) * (MBT_ * 256);
#pragma unroll
      for (int r = 0; r < 4; ++r) {
        const int m = mt * 16 + quad * 4 + r;
        float rr = sigm(ar[r] + b0r);
        float zz = sigm(az[r] + b0z);
        float nn = tanh_f(ani[r] + b0i + rr * (anh[r] + b0h));
        float hp = rse[r] ? 0.f : h0v[r];
        float hv = (1.f - zz) * nn + zz * hp;
        h0v[r] = hv;
        hw[m * 256 + colg] = f2bf(hv);
        if (wr) __builtin_nontemporal_store(hv, &out[((size_t)t * B_ + b0 + m) * HID_ + colg]);
      }
    }
    // ---- rendezvous: publish h0 slice; wait team h0[kk] and h1[kk-1] ----
    __syncthreads();   // drains vmem (compiler emits vmcnt(0) before barrier)
    if (tid == 0) {
      __hip_atomic_fetch_add(f0, 1, __ATOMIC_RELEASE, __HIP_MEMORY_SCOPE_AGENT);
      int cap = 0;
      while (__hip_atomic_load(f0, __ATOMIC_RELAXED, __HIP_MEMORY_SCOPE_AGENT)
                 < 8 * kk && cap < (1 << 16)) { __builtin_amdgcn_s_sleep(2); ++cap; }
      if (kk >= 2) {
        cap = 0;
        while (__hip_atomic_load(f1, __ATOMIC_RELAXED, __HIP_MEMORY_SCOPE_AGENT)
                   < 8 * (kk - 1) && cap < (1 << 16)) { __builtin_amdgcn_s_sleep(2); ++cap; }
      }
      // one acquire (buffer_inv) for both waits, instead of one per poll
      __builtin_amdgcn_fence(__ATOMIC_ACQUIRE, "agent");
    }
    __syncthreads();
    // refresh full-row A-frags: h0n[t] (fresh) and h1n[t-1]
    {
      const unsigned short* hr0 =
          hx0 + ((size_t)team * 2 + (kk & 1)) * (MBT_ * 256) + (mt * 16 + l15) * 256;
#pragma unroll
      for (int kc = 0; kc < 8; ++kc)
        h0A[kc] = *(const bf16x8v*)&hr0[kc * 32 + quad * 8];
      if (kk >= 2) {
        const unsigned short* hr1 =
            hx1 + ((size_t)team * 2 + ((kk - 1) & 1)) * (MBT_ * 256) + (mt * 16 + l15) * 256;
#pragma unroll
        for (int kc = 0; kc < 8; ++kc)
          h1A[kc] = *(const bf16x8v*)&hr1[kc * 32 + quad * 8];
      }
    }

    // ============ layer 1 ============
    ar = (f32x4){0.f, 0.f, 0.f, 0.f}; az = ar; ani = ar; anh = ar;
#pragma unroll
    for (int kc = 0; kc < 8; ++kc) {
      bf16x8v ai_ = h0A[kc];                 // h0n[t], unmasked
      bf16x8v am  = rs0 ? z8 : h1A[kc];      // mask*h1[t-1]
      const int o = kc * 32 + quad * 8;
      ar  = MFMA_B16(ai_, *(const bf16x8v*)&iR1[o], ar);
      az  = MFMA_B16(ai_, *(const bf16x8v*)&iZ1[o], az);
      ani = MFMA_B16(ai_, *(const bf16x8v*)&iN1[o], ani);
      ar  = MFMA_B16(am, *(const bf16x8v*)&hR1[o], ar);
      az  = MFMA_B16(am, *(const bf16x8v*)&hZ1[o], az);
      anh = MFMA_B16(am, *(const bf16x8v*)&hN1[o], anh);
    }
    // epilogue 1
    {
      unsigned short* hw = hx1 + ((size_t)team * 2 + (kk & 1)) * (MBT_ * 256);
#pragma unroll
      for (int r = 0; r < 4; ++r) {
        const int m = mt * 16 + quad * 4 + r;
        float rr = sigm(ar[r] + b1r);
        float zz = sigm(az[r] + b1z);
        float nn = tanh_f(ani[r] + b1i + rr * (anh[r] + b1h));
        float hp = rse[r] ? 0.f : h1v[r];
        float hv = (1.f - zz) * nn + zz * hp;
        h1v[r] = hv;
        hw[m * 256 + colg] = f2bf(hv);
        if (wr) __builtin_nontemporal_store(hv, &out[((size_t)t * B_ + b0 + m) * HID_ + 256 + colg]);
      }
    }
    __syncthreads();
    if (tid == 0)
      __hip_atomic_fetch_add(f1, 1, __ATOMIC_RELEASE, __HIP_MEMORY_SCOPE_AGENT);
    // (h1[kk] readers wait at next step's rendezvous; buffer-overwrite safety
    //  follows from flag0>=8kk implying all siblings finished step kk-1 reads)
  }
#undef RVAL
}

extern "C" void kernel_launch(void* const* d_in, const int* in_sizes, int n_in,
                              void* d_out, int out_size, void* d_ws, size_t ws_size,
                              hipStream_t stream) {
  const float* obs    = (const float*)d_in[0];
  const unsigned char* rst = (const unsigned char*)d_in[1];
  const float* h_init = (const float*)d_in[2];
  const float* W_lin  = (const float*)d_in[3];
  const float* b_lin  = (const float*)d_in[4];
  const float* w_ih0  = (const float*)d_in[5];
  const float* w_hh0  = (const float*)d_in[6];
  const float* b_ih0  = (const float*)d_in[7];
  const float* b_hh0  = (const float*)d_in[8];
  const float* w_ih1  = (const float*)d_in[9];
  const float* w_hh1  = (const float*)d_in[10];
  const float* b_ih1  = (const float*)d_in[11];
  const float* b_hh1  = (const float*)d_in[12];

  // workspace carve (re-initialized every launch; ws is re-poisoned by harness)
  char* w = (char*)d_ws;
  unsigned short* wcp   = (unsigned short*)(w);              // 98304 B
  unsigned short* whh0b = (unsigned short*)(w + 98304);      // 393216 B
  unsigned short* wih1b = (unsigned short*)(w + 491520);
  unsigned short* whh1b = (unsigned short*)(w + 884736);
  float*          bcp   = (float*)(w + 1277952);             // 3072 B
  int*            flagp = (int*)(w + 1281024);               // 16 B
  int*            flags = (int*)(w + 1281088);               // 32 teams * 512 B padded flags
  unsigned short* hx0   = (unsigned short*)(w + 1310720);    // 32*2*64*256*2 = 2 MiB
  unsigned short* hx1   = (unsigned short*)(w + 1310720 + 2097152);

  prep_conv<<<1152, 512, 0, stream>>>(w_hh0, w_ih1, w_hh1, rst, whh0b, flagp, flags);
  prep_wc<<<768, 64, 0, stream>>>(W_lin, b_lin, w_ih0, b_ih0, wcp, bcp);
  gru_main<<<256, 512, 0, stream>>>(obs, rst, h_init, wcp, whh0b, wih1b, whh1b,
                                    bcp, b_hh0, b_ih1, b_hh1, flagp,
                                    flags, flags + 64, hx0, hx1, (float*)d_out);
}

// Round 2
// 714.043 us; speedup vs baseline: 1.6565x; 1.4463x over previous
//
#include <hip/hip_runtime.h>

// RecurrentModel: 2-layer GRU stack. Persistent-weight team design.
// 32 teams x 8 blocks. Team = (batch-group of 64) x (time-chunk of 32).
// Block j of a team owns hidden cols [32j,32j+32) of BOTH layers; its weight
// row-slices live in LDS for the whole kernel. Per step, teams exchange
// h-state slices via d_ws buffers + per-team atomic flags.
// R1: per-team flag padding (512B), relaxed spin, s_sleep(2).
// R2: fence-free rendezvous — hx exchange uses per-access device-coherent
//     (RELAXED/AGENT atomic, sc1) stores+loads, flag adds RELAXED, acquire
//     fence removed. Kills the per-step buffer_wbl2/buffer_inv L2
//     maintenance storms (2 wbl2 + 1 inv per block per step). obs loads
//     software-pipelined one step ahead (L2 now stays warm).
#define T_    256
#define B_    256
#define IN_   64
#define HID_  512
#define LS_   256
#define G3_   768
#define TBS_  32     // timesteps per team
#define MBT_  64     // batch rows per team
#define WP_   264    // LDS weight row pitch in shorts (528B: 16B-aligned, 2-way-bank free)
#define FSTRIDE_ 128 // ints per team flag region (512 B); flag1 at +64 ints

typedef short bf16x8v __attribute__((ext_vector_type(8)));
typedef float f32x4  __attribute__((ext_vector_type(4)));
typedef unsigned long long u64;

#define MFMA_B16(A, B, C) __builtin_amdgcn_mfma_f32_16x16x32_bf16(A, B, C, 0, 0, 0)

__device__ __forceinline__ unsigned short f2bf(float f) {
  union { float f; unsigned u; } v; v.f = f;
  unsigned r = v.u + 0x7fffu + ((v.u >> 16) & 1u);   // RNE
  return (unsigned short)(r >> 16);
}
__device__ __forceinline__ float sigm(float x) { return 1.0f / (1.0f + __expf(-x)); }
__device__ __forceinline__ float tanh_f(float x) {
  x = fminf(fmaxf(x, -15.0f), 15.0f);
  float e = __expf(-2.0f * x);
  return (1.0f - e) / (1.0f + e);
}

// device-coherent (sc1) 2B store: visible at coherence point, no fence needed
__device__ __forceinline__ void st2_coh(unsigned short* p, unsigned short v) {
  __hip_atomic_store(p, v, __ATOMIC_RELAXED, __HIP_MEMORY_SCOPE_AGENT);
}
// device-coherent 16B load assembled from two 8B coherent loads
__device__ __forceinline__ bf16x8v ld16_coh(const unsigned short* p) {
  union { u64 q[2]; bf16x8v v; } u;
  u.q[0] = __hip_atomic_load((const u64*)p,     __ATOMIC_RELAXED, __HIP_MEMORY_SCOPE_AGENT);
  u.q[1] = __hip_atomic_load((const u64*)(p+4), __ATOMIC_RELAXED, __HIP_MEMORY_SCOPE_AGENT);
  return u.v;
}

// ---------------- prep 1: bf16 weight conversion + reset sniff + flag zero ----
__global__ void prep_conv(const float* __restrict__ whh0, const float* __restrict__ wih1,
                          const float* __restrict__ whh1, const unsigned char* __restrict__ rst,
                          unsigned short* __restrict__ dst, int* __restrict__ flagp,
                          int* __restrict__ flags) {
  const int idx = blockIdx.x * blockDim.x + threadIdx.x;
  const int N1 = G3_ * LS_;
  if (idx < 3 * N1) {
    float v;
    if (idx < N1)            v = whh0[idx];
    else if (idx < 2 * N1)   v = wih1[idx - N1];
    else                     v = whh1[idx - 2 * N1];
    dst[idx] = f2bf(v);
  }
  if (blockIdx.x == 1 && threadIdx.x < 64) {
    // zero per-team padded flags: flag0 at team*FSTRIDE_, flag1 at +64
    int tm = threadIdx.x & 31;
    flags[tm * FSTRIDE_ + ((threadIdx.x & 32) ? 64 : 0)] = 0;
  }
  if (blockIdx.x == 0) {
    __shared__ int f;
    if (threadIdx.x == 0) f = 0;
    __syncthreads();
    int any = 0;
    for (int i = 0; i < 8; ++i) {
      int off = threadIdx.x * 8 + i;
      if ((off & 3) && rst[off]) any = 1;
    }
    if (any) atomicOr(&f, 1);
    __syncthreads();
    if (threadIdx.x == 0) *flagp = f;   // 1 => byte-packed reset
  }
}

// ---------------- prep 2: fused embed W_c = w_ih0 @ W_lin, b_c --------------
__global__ void prep_wc(const float* __restrict__ W_lin, const float* __restrict__ b_lin,
                        const float* __restrict__ w_ih0, const float* __restrict__ b_ih0,
                        unsigned short* __restrict__ wc, float* __restrict__ bc) {
  const int n = blockIdx.x;
  const int i = threadIdx.x;
  const float* wrow = w_ih0 + (size_t)n * HID_;
  float acc = 0.f;
  for (int h = 0; h < HID_; ++h) acc += wrow[h] * W_lin[h * IN_ + i];
  wc[n * IN_ + i] = f2bf(acc);
  float pb = 0.f;
  for (int h = i; h < HID_; h += 64) pb += wrow[h] * b_lin[h];
  __shared__ float red[64];
  red[i] = pb;
  __syncthreads();
  if (i == 0) {
    float s = 0.f;
    for (int k = 0; k < 64; ++k) s += red[k];
    bc[n] = s + b_ih0[n];
  }
}

// ---------------- main: persistent-weight recurrent kernel ------------------
__global__ __launch_bounds__(512, 2) void gru_main(
    const float* __restrict__ obs, const unsigned char* __restrict__ rst,
    const float* __restrict__ h_init,
    const unsigned short* __restrict__ wc,     // [768][64] bf16 (global, L2-hot)
    const unsigned short* __restrict__ whh0g,  // [768][256] bf16
    const unsigned short* __restrict__ wih1g, const unsigned short* __restrict__ whh1g,
    const float* __restrict__ bcp, const float* __restrict__ bhh0,
    const float* __restrict__ bih1, const float* __restrict__ bhh1,
    const int* __restrict__ flagp, int* __restrict__ flag0, int* __restrict__ flag1,
    unsigned short* __restrict__ hx0, unsigned short* __restrict__ hx1,
    float* __restrict__ out) {

  // Weight slices, persistent all-kernel: [whh0 | wih1 | whh1], 96 rows x 264 pitch
  __shared__ __align__(16) unsigned short wlds[3 * 96 * WP_];   // 152064 B
  __shared__ int s_sm[64];
  __shared__ int s_start_sh;

  const int tid  = threadIdx.x;
  const int lane = tid & 63;
  const int wave = tid >> 6;
  const int l15  = lane & 15;
  const int quad = lane >> 4;
  const int mt   = wave & 3;            // m16 tile (batch rows mt*16..+16)
  const int c16  = (wave >> 2) * 16;    // col-16 half of the 32-col slice

  // block -> (team, slice j); bx&7 ~ XCD heuristic (correctness-independent)
  const int x  = blockIdx.x;
  const int cx = x & 7, m8 = x >> 3;
  const int j  = m8 & 7;                // col-slice 0..7
  const int team = cx * 4 + (m8 >> 3);  // 0..31 (4 teams per XCD)
  const int bg = team & 3, tc = team >> 2;
  const int b0 = bg * MBT_, t0 = tc * TBS_;

  // per-team private flag words (512-B stride kills cross-team line contention)
  int* f0 = flag0 + team * FSTRIDE_;
  int* f1 = flag1 + team * FSTRIDE_;

  const int flag = *flagp;
#define RVAL(i) (rst[flag ? (i) : ((i) << 2)] != 0)

  // ---- stage weight slices into LDS (once) ----
#pragma unroll
  for (int q = 0; q < 3; ++q) {
    const unsigned short* src = (q == 0) ? whh0g : (q == 1) ? wih1g : whh1g;
    for (int cid = tid; cid < 96 * 32; cid += 512) {      // 16B chunks
      int lr = cid >> 5, off8 = (cid & 31) * 8;           // row, short-offset
      int g = lr >> 5, cc = lr & 31;
      int grow = (g << 8) + (j << 5) + cc;                // g*256 + j*32 + cc
      *(f32x4*)&wlds[(q * 96 + lr) * WP_ + off8] =
          *(const f32x4*)&src[(size_t)grow * 256 + off8];
    }
  }

  // ---- per-lane biases (cols this wave computes) ----
  const int colg = j * 32 + c16 + l15;   // 0..255 within layer
  const float b0r = bcp[colg] + bhh0[colg];
  const float b0z = bcp[256 + colg] + bhh0[256 + colg];
  const float b0i = bcp[512 + colg];
  const float b0h = bhh0[512 + colg];
  const float b1r = bih1[colg] + bhh1[colg];
  const float b1z = bih1[256 + colg] + bhh1[256 + colg];
  const float b1i = bih1[512 + colg];
  const float b1h = bhh1[512 + colg];

  // ---- team-uniform safe start (last reset <= t0 across the 64 batch rows) ----
  if (tid < 64) {
    int s = 0;
    for (int tt = t0; tt >= 1; --tt) {
      if (RVAL(tt * B_ + b0 + tid)) { s = tt; break; }
    }
    s_sm[tid] = s;
  }
  __syncthreads();
  if (tid == 0) {
    int s = s_sm[0];
    for (int k = 1; k < 64; ++k) s = s < s_sm[k] ? s : s_sm[k];
    s_start_sh = s;
  }
  __syncthreads();
  const int s_start = s_start_sh;   // identical across the 8 sibling blocks

  // ---- init A-fragments (full h rows mt*16+l15) and fp32 carries ----
  bf16x8v h0A[8], h1A[8];
  const bf16x8v z8 = {0, 0, 0, 0, 0, 0, 0, 0};
#pragma unroll
  for (int kc = 0; kc < 8; ++kc) { h0A[kc] = z8; h1A[kc] = z8; }
  float h0v[4] = {0.f, 0.f, 0.f, 0.f}, h1v[4] = {0.f, 0.f, 0.f, 0.f};
  if (s_start == 0) {
    const float* hrow = h_init + (size_t)(b0 + mt * 16 + l15) * HID_;
#pragma unroll
    for (int kc = 0; kc < 8; ++kc) {
      f32x4 u0 = *(const f32x4*)(hrow + kc * 32 + quad * 8);
      f32x4 u1 = *(const f32x4*)(hrow + kc * 32 + quad * 8 + 4);
      f32x4 v0 = *(const f32x4*)(hrow + 256 + kc * 32 + quad * 8);
      f32x4 v1 = *(const f32x4*)(hrow + 256 + kc * 32 + quad * 8 + 4);
      bf16x8v a, b;
#pragma unroll
      for (int e = 0; e < 4; ++e) {
        a[e] = (short)f2bf(u0[e]); a[4 + e] = (short)f2bf(u1[e]);
        b[e] = (short)f2bf(v0[e]); b[4 + e] = (short)f2bf(v1[e]);
      }
      h0A[kc] = a; h1A[kc] = b;
    }
#pragma unroll
    for (int r = 0; r < 4; ++r) {
      const int m = mt * 16 + quad * 4 + r;
      h0v[r] = h_init[(size_t)(b0 + m) * HID_ + colg];
      h1v[r] = h_init[(size_t)(b0 + m) * HID_ + 256 + colg];
    }
  }

  const unsigned short* wR0 = &wlds[(0 * 96 + 0 * 32 + c16 + l15) * WP_];
  const unsigned short* wZ0 = &wlds[(0 * 96 + 1 * 32 + c16 + l15) * WP_];
  const unsigned short* wN0 = &wlds[(0 * 96 + 2 * 32 + c16 + l15) * WP_];
  const unsigned short* iR1 = &wlds[(1 * 96 + 0 * 32 + c16 + l15) * WP_];
  const unsigned short* iZ1 = &wlds[(1 * 96 + 1 * 32 + c16 + l15) * WP_];
  const unsigned short* iN1 = &wlds[(1 * 96 + 2 * 32 + c16 + l15) * WP_];
  const unsigned short* hR1 = &wlds[(2 * 96 + 0 * 32 + c16 + l15) * WP_];
  const unsigned short* hZ1 = &wlds[(2 * 96 + 1 * 32 + c16 + l15) * WP_];
  const unsigned short* hN1 = &wlds[(2 * 96 + 2 * 32 + c16 + l15) * WP_];

  // obs software pipeline: raw f32x4 regs for the CURRENT step, prefetched
  // one step ahead (consumed at L0 before the rendezvous, refilled after it)
  f32x4 ou0a, ou0b, ou1a, ou1b;
  {
    const float* po = obs + ((size_t)s_start * B_ + b0 + mt * 16 + l15) * IN_;
    ou0a = __builtin_nontemporal_load((const f32x4*)(po + quad * 8));
    ou0b = __builtin_nontemporal_load((const f32x4*)(po + quad * 8 + 4));
    ou1a = __builtin_nontemporal_load((const f32x4*)(po + 32 + quad * 8));
    ou1b = __builtin_nontemporal_load((const f32x4*)(po + 32 + quad * 8 + 4));
  }

  for (int t = s_start; t < t0 + TBS_; ++t) {
    const int  kk = t - s_start + 1;          // 1-based team step counter
    const bool wr = (t >= t0);
    const bool rs0 = RVAL(t * B_ + b0 + mt * 16 + l15);   // A-row mask
    bool rse[4];
#pragma unroll
    for (int r = 0; r < 4; ++r) rse[r] = RVAL(t * B_ + b0 + mt * 16 + quad * 4 + r);

    // ============ layer 0 ============
    f32x4 ar = {0.f, 0.f, 0.f, 0.f}, az = ar, ani = ar, anh = ar;
    // input side: obs @ W_c^T (K=64), obs raw regs prefetched last iter
    {
#pragma unroll
      for (int kc = 0; kc < 2; ++kc) {
        f32x4 u0 = kc ? ou1a : ou0a;
        f32x4 u1 = kc ? ou1b : ou0b;
        bf16x8v oA;
#pragma unroll
        for (int e = 0; e < 4; ++e) { oA[e] = (short)f2bf(u0[e]); oA[4 + e] = (short)f2bf(u1[e]); }
        const size_t wo = (size_t)colg * 64 + kc * 32 + quad * 8;
        bf16x8v br = *(const bf16x8v*)&wc[wo];
        bf16x8v bz = *(const bf16x8v*)&wc[wo + (size_t)256 * 64];
        bf16x8v bn = *(const bf16x8v*)&wc[wo + (size_t)512 * 64];
        ar  = MFMA_B16(oA, br, ar);
        az  = MFMA_B16(oA, bz, az);
        ani = MFMA_B16(oA, bn, ani);
      }
    }
    // h side: (mask*h0[t-1]) @ whh0^T (K=256, LDS weights)
#pragma unroll
    for (int kc = 0; kc < 8; ++kc) {
      bf16x8v am = rs0 ? z8 : h0A[kc];
      const int o = kc * 32 + quad * 8;
      ar  = MFMA_B16(am, *(const bf16x8v*)&wR0[o], ar);
      az  = MFMA_B16(am, *(const bf16x8v*)&wZ0[o], az);
      anh = MFMA_B16(am, *(const bf16x8v*)&wN0[o], anh);
    }
    // epilogue 0: fp32 carry, publish slice (coherent 2B stores), out
    {
      unsigned short* hw = hx0 + ((size_t)team * 2 + (kk & 1)) * (MBT_ * 256);
#pragma unroll
      for (int r = 0; r < 4; ++r) {
        const int m = mt * 16 + quad * 4 + r;
        float rr = sigm(ar[r] + b0r);
        float zz = sigm(az[r] + b0z);
        float nn = tanh_f(ani[r] + b0i + rr * (anh[r] + b0h));
        float hp = rse[r] ? 0.f : h0v[r];
        float hv = (1.f - zz) * nn + zz * hp;
        h0v[r] = hv;
        st2_coh(hw + m * 256 + colg, f2bf(hv));
        if (wr) __builtin_nontemporal_store(hv, &out[((size_t)t * B_ + b0 + m) * HID_ + colg]);
      }
    }
    // ---- rendezvous: publish h0 slice; wait team h0[kk] and h1[kk-1] ----
    // barrier drain (vmcnt(0)) completes the sc1 stores at the coherence
    // point before tid0 signals -> RELAXED add suffices, no wbl2.
    __syncthreads();
    if (tid == 0) {
      __hip_atomic_fetch_add(f0, 1, __ATOMIC_RELAXED, __HIP_MEMORY_SCOPE_AGENT);
      int cap = 0;
      while (__hip_atomic_load(f0, __ATOMIC_RELAXED, __HIP_MEMORY_SCOPE_AGENT)
                 < 8 * kk && cap < (1 << 16)) { __builtin_amdgcn_s_sleep(2); ++cap; }
      if (kk >= 2) {
        cap = 0;
        while (__hip_atomic_load(f1, __ATOMIC_RELAXED, __HIP_MEMORY_SCOPE_AGENT)
                   < 8 * (kk - 1) && cap < (1 << 16)) { __builtin_amdgcn_s_sleep(2); ++cap; }
      }
      // no acquire fence: reader loads below are per-access coherent (sc1)
    }
    __syncthreads();
    // prefetch obs for step t+1 (overlaps with the coherent A-frag refresh)
    {
      const int tn = (t + 1 < t0 + TBS_) ? t + 1 : t;
      const float* po = obs + ((size_t)tn * B_ + b0 + mt * 16 + l15) * IN_;
      ou0a = __builtin_nontemporal_load((const f32x4*)(po + quad * 8));
      ou0b = __builtin_nontemporal_load((const f32x4*)(po + quad * 8 + 4));
      ou1a = __builtin_nontemporal_load((const f32x4*)(po + 32 + quad * 8));
      ou1b = __builtin_nontemporal_load((const f32x4*)(po + 32 + quad * 8 + 4));
    }
    // refresh full-row A-frags: h0n[t] (fresh) and h1n[t-1] — coherent loads
    {
      const unsigned short* hr0 =
          hx0 + ((size_t)team * 2 + (kk & 1)) * (MBT_ * 256) + (mt * 16 + l15) * 256;
#pragma unroll
      for (int kc = 0; kc < 8; ++kc)
        h0A[kc] = ld16_coh(hr0 + kc * 32 + quad * 8);
      if (kk >= 2) {
        const unsigned short* hr1 =
            hx1 + ((size_t)team * 2 + ((kk - 1) & 1)) * (MBT_ * 256) + (mt * 16 + l15) * 256;
#pragma unroll
        for (int kc = 0; kc < 8; ++kc)
          h1A[kc] = ld16_coh(hr1 + kc * 32 + quad * 8);
      }
    }

    // ============ layer 1 ============
    ar = (f32x4){0.f, 0.f, 0.f, 0.f}; az = ar; ani = ar; anh = ar;
#pragma unroll
    for (int kc = 0; kc < 8; ++kc) {
      bf16x8v ai_ = h0A[kc];                 // h0n[t], unmasked
      bf16x8v am  = rs0 ? z8 : h1A[kc];      // mask*h1[t-1]
      const int o = kc * 32 + quad * 8;
      ar  = MFMA_B16(ai_, *(const bf16x8v*)&iR1[o], ar);
      az  = MFMA_B16(ai_, *(const bf16x8v*)&iZ1[o], az);
      ani = MFMA_B16(ai_, *(const bf16x8v*)&iN1[o], ani);
      ar  = MFMA_B16(am, *(const bf16x8v*)&hR1[o], ar);
      az  = MFMA_B16(am, *(const bf16x8v*)&hZ1[o], az);
      anh = MFMA_B16(am, *(const bf16x8v*)&hN1[o], anh);
    }
    // epilogue 1
    {
      unsigned short* hw = hx1 + ((size_t)team * 2 + (kk & 1)) * (MBT_ * 256);
#pragma unroll
      for (int r = 0; r < 4; ++r) {
        const int m = mt * 16 + quad * 4 + r;
        float rr = sigm(ar[r] + b1r);
        float zz = sigm(az[r] + b1z);
        float nn = tanh_f(ani[r] + b1i + rr * (anh[r] + b1h));
        float hp = rse[r] ? 0.f : h1v[r];
        float hv = (1.f - zz) * nn + zz * hp;
        h1v[r] = hv;
        st2_coh(hw + m * 256 + colg, f2bf(hv));
        if (wr) __builtin_nontemporal_store(hv, &out[((size_t)t * B_ + b0 + m) * HID_ + 256 + colg]);
      }
    }
    __syncthreads();   // drains sc1 stores before the f1 signal
    if (tid == 0)
      __hip_atomic_fetch_add(f1, 1, __ATOMIC_RELAXED, __HIP_MEMORY_SCOPE_AGENT);
    // (h1[kk] readers wait at next step's rendezvous; buffer-overwrite safety
    //  follows from flag0>=8kk implying all siblings finished step kk-1 reads)
  }
#undef RVAL
}

extern "C" void kernel_launch(void* const* d_in, const int* in_sizes, int n_in,
                              void* d_out, int out_size, void* d_ws, size_t ws_size,
                              hipStream_t stream) {
  const float* obs    = (const float*)d_in[0];
  const unsigned char* rst = (const unsigned char*)d_in[1];
  const float* h_init = (const float*)d_in[2];
  const float* W_lin  = (const float*)d_in[3];
  const float* b_lin  = (const float*)d_in[4];
  const float* w_ih0  = (const float*)d_in[5];
  const float* w_hh0  = (const float*)d_in[6];
  const float* b_ih0  = (const float*)d_in[7];
  const float* b_hh0  = (const float*)d_in[8];
  const float* w_ih1  = (const float*)d_in[9];
  const float* w_hh1  = (const float*)d_in[10];
  const float* b_ih1  = (const float*)d_in[11];
  const float* b_hh1  = (const float*)d_in[12];

  // workspace carve (re-initialized every launch; ws is re-poisoned by harness)
  char* w = (char*)d_ws;
  unsigned short* wcp   = (unsigned short*)(w);              // 98304 B
  unsigned short* whh0b = (unsigned short*)(w + 98304);      // 393216 B
  unsigned short* wih1b = (unsigned short*)(w + 491520);
  unsigned short* whh1b = (unsigned short*)(w + 884736);
  float*          bcp   = (float*)(w + 1277952);             // 3072 B
  int*            flagp = (int*)(w + 1281024);               // 16 B
  int*            flags = (int*)(w + 1281088);               // 32 teams * 512 B padded flags
  unsigned short* hx0   = (unsigned short*)(w + 1310720);    // 32*2*64*256*2 = 2 MiB
  unsigned short* hx1   = (unsigned short*)(w + 1310720 + 2097152);

  prep_conv<<<1152, 512, 0, stream>>>(w_hh0, w_ih1, w_hh1, rst, whh0b, flagp, flags);
  prep_wc<<<768, 64, 0, stream>>>(W_lin, b_lin, w_ih0, b_ih0, wcp, bcp);
  gru_main<<<256, 512, 0, stream>>>(obs, rst, h_init, wcp, whh0b, wih1b, whh1b,
                                    bcp, b_hh0, b_ih1, b_hh1, flagp,
                                    flags, flags + 64, hx0, hx1, (float*)d_out);
}

// Round 3
// 658.198 us; speedup vs baseline: 1.7971x; 1.0848x over previous
//
#include <hip/hip_runtime.h>

// RecurrentModel: 2-layer GRU stack. Persistent-weight team design.
// 32 teams x 8 blocks. Team = (batch-group of 64) x (time-chunk of 32).
// Block j of a team owns hidden cols [32j,32j+32) of BOTH layers; its weight
// row-slices live in LDS for the whole kernel. Per step, teams exchange
// h-state slices via d_ws buffers + per-team atomic flags.
// R1: per-team flag padding (512B), relaxed spin, s_sleep(2).
// R2: fence-free rendezvous — sc1 per-access coherent exchange, no wbl2/inv.
// R3: SINGLE rendezvous per step. flag1 deleted: sibling's f0-add at step kk
//     occurs after its barrier drained the h1[kk-1] publish, so f0>=8kk
//     already implies h1[kk-1] visible. h1-publish drain now hides under the
//     next step's L0 compute. out NT-stores moved off the pre-signal drain
//     (issued post-wait from registers); A-frag loads issued first post-wait.
#define T_    256
#define B_    256
#define IN_   64
#define HID_  512
#define LS_   256
#define G3_   768
#define TBS_  32     // timesteps per team
#define MBT_  64     // batch rows per team
#define WP_   264    // LDS weight row pitch in shorts (528B: 16B-aligned, 2-way-bank free)
#define FSTRIDE_ 128 // ints per team flag region (512 B)

typedef short bf16x8v __attribute__((ext_vector_type(8)));
typedef float f32x4  __attribute__((ext_vector_type(4)));
typedef unsigned long long u64;

#define MFMA_B16(A, B, C) __builtin_amdgcn_mfma_f32_16x16x32_bf16(A, B, C, 0, 0, 0)

__device__ __forceinline__ unsigned short f2bf(float f) {
  union { float f; unsigned u; } v; v.f = f;
  unsigned r = v.u + 0x7fffu + ((v.u >> 16) & 1u);   // RNE
  return (unsigned short)(r >> 16);
}
__device__ __forceinline__ float sigm(float x) { return 1.0f / (1.0f + __expf(-x)); }
__device__ __forceinline__ float tanh_f(float x) {
  x = fminf(fmaxf(x, -15.0f), 15.0f);
  float e = __expf(-2.0f * x);
  return (1.0f - e) / (1.0f + e);
}

// device-coherent (sc1) 2B store: visible at coherence point, no fence needed
__device__ __forceinline__ void st2_coh(unsigned short* p, unsigned short v) {
  __hip_atomic_store(p, v, __ATOMIC_RELAXED, __HIP_MEMORY_SCOPE_AGENT);
}
// device-coherent 16B load assembled from two 8B coherent loads
__device__ __forceinline__ bf16x8v ld16_coh(const unsigned short* p) {
  union { u64 q[2]; bf16x8v v; } u;
  u.q[0] = __hip_atomic_load((const u64*)p,     __ATOMIC_RELAXED, __HIP_MEMORY_SCOPE_AGENT);
  u.q[1] = __hip_atomic_load((const u64*)(p+4), __ATOMIC_RELAXED, __HIP_MEMORY_SCOPE_AGENT);
  return u.v;
}

// ---------------- prep 1: bf16 weight conversion + reset sniff + flag zero ----
__global__ void prep_conv(const float* __restrict__ whh0, const float* __restrict__ wih1,
                          const float* __restrict__ whh1, const unsigned char* __restrict__ rst,
                          unsigned short* __restrict__ dst, int* __restrict__ flagp,
                          int* __restrict__ flags) {
  const int idx = blockIdx.x * blockDim.x + threadIdx.x;
  const int N1 = G3_ * LS_;
  if (idx < 3 * N1) {
    float v;
    if (idx < N1)            v = whh0[idx];
    else if (idx < 2 * N1)   v = wih1[idx - N1];
    else                     v = whh1[idx - 2 * N1];
    dst[idx] = f2bf(v);
  }
  if (blockIdx.x == 1 && threadIdx.x < 32) {
    flags[threadIdx.x * FSTRIDE_] = 0;   // per-team padded f0
  }
  if (blockIdx.x == 0) {
    __shared__ int f;
    if (threadIdx.x == 0) f = 0;
    __syncthreads();
    int any = 0;
    for (int i = 0; i < 8; ++i) {
      int off = threadIdx.x * 8 + i;
      if ((off & 3) && rst[off]) any = 1;
    }
    if (any) atomicOr(&f, 1);
    __syncthreads();
    if (threadIdx.x == 0) *flagp = f;   // 1 => byte-packed reset
  }
}

// ---------------- prep 2: fused embed W_c = w_ih0 @ W_lin, b_c --------------
__global__ void prep_wc(const float* __restrict__ W_lin, const float* __restrict__ b_lin,
                        const float* __restrict__ w_ih0, const float* __restrict__ b_ih0,
                        unsigned short* __restrict__ wc, float* __restrict__ bc) {
  const int n = blockIdx.x;
  const int i = threadIdx.x;
  const float* wrow = w_ih0 + (size_t)n * HID_;
  float acc = 0.f;
  for (int h = 0; h < HID_; ++h) acc += wrow[h] * W_lin[h * IN_ + i];
  wc[n * IN_ + i] = f2bf(acc);
  float pb = 0.f;
  for (int h = i; h < HID_; h += 64) pb += wrow[h] * b_lin[h];
  __shared__ float red[64];
  red[i] = pb;
  __syncthreads();
  if (i == 0) {
    float s = 0.f;
    for (int k = 0; k < 64; ++k) s += red[k];
    bc[n] = s + b_ih0[n];
  }
}

// ---------------- main: persistent-weight recurrent kernel ------------------
__global__ __launch_bounds__(512, 2) void gru_main(
    const float* __restrict__ obs, const unsigned char* __restrict__ rst,
    const float* __restrict__ h_init,
    const unsigned short* __restrict__ wc,     // [768][64] bf16 (global, L2-hot)
    const unsigned short* __restrict__ whh0g,  // [768][256] bf16
    const unsigned short* __restrict__ wih1g, const unsigned short* __restrict__ whh1g,
    const float* __restrict__ bcp, const float* __restrict__ bhh0,
    const float* __restrict__ bih1, const float* __restrict__ bhh1,
    const int* __restrict__ flagp, int* __restrict__ flag0,
    unsigned short* __restrict__ hx0, unsigned short* __restrict__ hx1,
    float* __restrict__ out) {

  // Weight slices, persistent all-kernel: [whh0 | wih1 | whh1], 96 rows x 264 pitch
  __shared__ __align__(16) unsigned short wlds[3 * 96 * WP_];   // 152064 B
  __shared__ int s_sm[64];
  __shared__ int s_start_sh;

  const int tid  = threadIdx.x;
  const int lane = tid & 63;
  const int wave = tid >> 6;
  const int l15  = lane & 15;
  const int quad = lane >> 4;
  const int mt   = wave & 3;            // m16 tile (batch rows mt*16..+16)
  const int c16  = (wave >> 2) * 16;    // col-16 half of the 32-col slice

  // block -> (team, slice j); bx&7 ~ XCD heuristic (correctness-independent)
  const int x  = blockIdx.x;
  const int cx = x & 7, m8 = x >> 3;
  const int j  = m8 & 7;                // col-slice 0..7
  const int team = cx * 4 + (m8 >> 3);  // 0..31 (4 teams per XCD)
  const int bg = team & 3, tc = team >> 2;
  const int b0 = bg * MBT_, t0 = tc * TBS_;

  // per-team private flag word (512-B stride kills cross-team line contention)
  int* f0 = flag0 + team * FSTRIDE_;

  const int flag = *flagp;
#define RVAL(i) (rst[flag ? (i) : ((i) << 2)] != 0)

  // ---- stage weight slices into LDS (once) ----
#pragma unroll
  for (int q = 0; q < 3; ++q) {
    const unsigned short* src = (q == 0) ? whh0g : (q == 1) ? wih1g : whh1g;
    for (int cid = tid; cid < 96 * 32; cid += 512) {      // 16B chunks
      int lr = cid >> 5, off8 = (cid & 31) * 8;           // row, short-offset
      int g = lr >> 5, cc = lr & 31;
      int grow = (g << 8) + (j << 5) + cc;                // g*256 + j*32 + cc
      *(f32x4*)&wlds[(q * 96 + lr) * WP_ + off8] =
          *(const f32x4*)&src[(size_t)grow * 256 + off8];
    }
  }

  // ---- per-lane biases (cols this wave computes) ----
  const int colg = j * 32 + c16 + l15;   // 0..255 within layer
  const float b0r = bcp[colg] + bhh0[colg];
  const float b0z = bcp[256 + colg] + bhh0[256 + colg];
  const float b0i = bcp[512 + colg];
  const float b0h = bhh0[512 + colg];
  const float b1r = bih1[colg] + bhh1[colg];
  const float b1z = bih1[256 + colg] + bhh1[256 + colg];
  const float b1i = bih1[512 + colg];
  const float b1h = bhh1[512 + colg];

  // ---- team-uniform safe start (last reset <= t0 across the 64 batch rows) ----
  if (tid < 64) {
    int s = 0;
    for (int tt = t0; tt >= 1; --tt) {
      if (RVAL(tt * B_ + b0 + tid)) { s = tt; break; }
    }
    s_sm[tid] = s;
  }
  __syncthreads();
  if (tid == 0) {
    int s = s_sm[0];
    for (int k = 1; k < 64; ++k) s = s < s_sm[k] ? s : s_sm[k];
    s_start_sh = s;
  }
  __syncthreads();
  const int s_start = s_start_sh;   // identical across the 8 sibling blocks

  // ---- init A-fragments (full h rows mt*16+l15) and fp32 carries ----
  bf16x8v h0A[8], h1A[8];
  const bf16x8v z8 = {0, 0, 0, 0, 0, 0, 0, 0};
#pragma unroll
  for (int kc = 0; kc < 8; ++kc) { h0A[kc] = z8; h1A[kc] = z8; }
  float h0v[4] = {0.f, 0.f, 0.f, 0.f}, h1v[4] = {0.f, 0.f, 0.f, 0.f};
  if (s_start == 0) {
    const float* hrow = h_init + (size_t)(b0 + mt * 16 + l15) * HID_;
#pragma unroll
    for (int kc = 0; kc < 8; ++kc) {
      f32x4 u0 = *(const f32x4*)(hrow + kc * 32 + quad * 8);
      f32x4 u1 = *(const f32x4*)(hrow + kc * 32 + quad * 8 + 4);
      f32x4 v0 = *(const f32x4*)(hrow + 256 + kc * 32 + quad * 8);
      f32x4 v1 = *(const f32x4*)(hrow + 256 + kc * 32 + quad * 8 + 4);
      bf16x8v a, b;
#pragma unroll
      for (int e = 0; e < 4; ++e) {
        a[e] = (short)f2bf(u0[e]); a[4 + e] = (short)f2bf(u1[e]);
        b[e] = (short)f2bf(v0[e]); b[4 + e] = (short)f2bf(v1[e]);
      }
      h0A[kc] = a; h1A[kc] = b;
    }
#pragma unroll
    for (int r = 0; r < 4; ++r) {
      const int m = mt * 16 + quad * 4 + r;
      h0v[r] = h_init[(size_t)(b0 + m) * HID_ + colg];
      h1v[r] = h_init[(size_t)(b0 + m) * HID_ + 256 + colg];
    }
  }

  const unsigned short* wR0 = &wlds[(0 * 96 + 0 * 32 + c16 + l15) * WP_];
  const unsigned short* wZ0 = &wlds[(0 * 96 + 1 * 32 + c16 + l15) * WP_];
  const unsigned short* wN0 = &wlds[(0 * 96 + 2 * 32 + c16 + l15) * WP_];
  const unsigned short* iR1 = &wlds[(1 * 96 + 0 * 32 + c16 + l15) * WP_];
  const unsigned short* iZ1 = &wlds[(1 * 96 + 1 * 32 + c16 + l15) * WP_];
  const unsigned short* iN1 = &wlds[(1 * 96 + 2 * 32 + c16 + l15) * WP_];
  const unsigned short* hR1 = &wlds[(2 * 96 + 0 * 32 + c16 + l15) * WP_];
  const unsigned short* hZ1 = &wlds[(2 * 96 + 1 * 32 + c16 + l15) * WP_];
  const unsigned short* hN1 = &wlds[(2 * 96 + 2 * 32 + c16 + l15) * WP_];

  // obs software pipeline: raw f32x4 regs for the CURRENT step, prefetched
  // one step ahead (consumed at L0 before the rendezvous, refilled after it)
  f32x4 ou0a, ou0b, ou1a, ou1b;
  {
    const float* po = obs + ((size_t)s_start * B_ + b0 + mt * 16 + l15) * IN_;
    ou0a = __builtin_nontemporal_load((const f32x4*)(po + quad * 8));
    ou0b = __builtin_nontemporal_load((const f32x4*)(po + quad * 8 + 4));
    ou1a = __builtin_nontemporal_load((const f32x4*)(po + 32 + quad * 8));
    ou1b = __builtin_nontemporal_load((const f32x4*)(po + 32 + quad * 8 + 4));
  }

  for (int t = s_start; t < t0 + TBS_; ++t) {
    const int  kk = t - s_start + 1;          // 1-based team step counter
    const bool wr = (t >= t0);
    const bool rs0 = RVAL(t * B_ + b0 + mt * 16 + l15);   // A-row mask
    bool rse[4];
#pragma unroll
    for (int r = 0; r < 4; ++r) rse[r] = RVAL(t * B_ + b0 + mt * 16 + quad * 4 + r);

    // ============ layer 0 ============
    f32x4 ar = {0.f, 0.f, 0.f, 0.f}, az = ar, ani = ar, anh = ar;
    // input side: obs @ W_c^T (K=64), obs raw regs prefetched last iter
    {
#pragma unroll
      for (int kc = 0; kc < 2; ++kc) {
        f32x4 u0 = kc ? ou1a : ou0a;
        f32x4 u1 = kc ? ou1b : ou0b;
        bf16x8v oA;
#pragma unroll
        for (int e = 0; e < 4; ++e) { oA[e] = (short)f2bf(u0[e]); oA[4 + e] = (short)f2bf(u1[e]); }
        const size_t wo = (size_t)colg * 64 + kc * 32 + quad * 8;
        bf16x8v br = *(const bf16x8v*)&wc[wo];
        bf16x8v bz = *(const bf16x8v*)&wc[wo + (size_t)256 * 64];
        bf16x8v bn = *(const bf16x8v*)&wc[wo + (size_t)512 * 64];
        ar  = MFMA_B16(oA, br, ar);
        az  = MFMA_B16(oA, bz, az);
        ani = MFMA_B16(oA, bn, ani);
      }
    }
    // h side: (mask*h0[t-1]) @ whh0^T (K=256, LDS weights)
#pragma unroll
    for (int kc = 0; kc < 8; ++kc) {
      bf16x8v am = rs0 ? z8 : h0A[kc];
      const int o = kc * 32 + quad * 8;
      ar  = MFMA_B16(am, *(const bf16x8v*)&wR0[o], ar);
      az  = MFMA_B16(am, *(const bf16x8v*)&wZ0[o], az);
      anh = MFMA_B16(am, *(const bf16x8v*)&wN0[o], anh);
    }
    // epilogue 0: fp32 carry, publish slice (coherent 2B stores). out deferred.
    {
      unsigned short* hw = hx0 + ((size_t)team * 2 + (kk & 1)) * (MBT_ * 256);
#pragma unroll
      for (int r = 0; r < 4; ++r) {
        const int m = mt * 16 + quad * 4 + r;
        float rr = sigm(ar[r] + b0r);
        float zz = sigm(az[r] + b0z);
        float nn = tanh_f(ani[r] + b0i + rr * (anh[r] + b0h));
        float hp = rse[r] ? 0.f : h0v[r];
        float hv = (1.f - zz) * nn + zz * hp;
        h0v[r] = hv;
        st2_coh(hw + m * 256 + colg, f2bf(hv));
      }
    }
    // ---- SINGLE rendezvous: the barrier's vmcnt(0) drain covers h0[kk]
    // stores AND last iter's h1[kk-1] stores (hidden under L0 compute).
    // f0>=8kk therefore implies: all siblings published h0[kk] and h1[kk-1].
    __syncthreads();
    if (tid == 0) {
      __hip_atomic_fetch_add(f0, 1, __ATOMIC_RELAXED, __HIP_MEMORY_SCOPE_AGENT);
      int cap = 0;
      while (__hip_atomic_load(f0, __ATOMIC_RELAXED, __HIP_MEMORY_SCOPE_AGENT)
                 < 8 * kk && cap < (1 << 16)) { __builtin_amdgcn_s_sleep(2); ++cap; }
      // no acquire fence: reader loads below are per-access coherent (sc1)
    }
    __syncthreads();
    // A-frag refresh FIRST (heads the VMEM queue; L1 MFMA waits on these):
    // h0n[t] (fresh) and h1n[t-1] — coherent loads
    {
      const unsigned short* hr0 =
          hx0 + ((size_t)team * 2 + (kk & 1)) * (MBT_ * 256) + (mt * 16 + l15) * 256;
#pragma unroll
      for (int kc = 0; kc < 8; ++kc)
        h0A[kc] = ld16_coh(hr0 + kc * 32 + quad * 8);
      if (kk >= 2) {
        const unsigned short* hr1 =
            hx1 + ((size_t)team * 2 + ((kk - 1) & 1)) * (MBT_ * 256) + (mt * 16 + l15) * 256;
#pragma unroll
        for (int kc = 0; kc < 8; ++kc)
          h1A[kc] = ld16_coh(hr1 + kc * 32 + quad * 8);
      }
    }
    // deferred out stores (off the rendezvous path): L0[t] and L1[t-1]
    if (wr) {
#pragma unroll
      for (int r = 0; r < 4; ++r) {
        const int m = mt * 16 + quad * 4 + r;
        __builtin_nontemporal_store(h0v[r], &out[((size_t)t * B_ + b0 + m) * HID_ + colg]);
      }
    }
    if (t - 1 >= t0) {
#pragma unroll
      for (int r = 0; r < 4; ++r) {
        const int m = mt * 16 + quad * 4 + r;
        __builtin_nontemporal_store(h1v[r],
            &out[((size_t)(t - 1) * B_ + b0 + m) * HID_ + 256 + colg]);
      }
    }
    // prefetch obs for step t+1
    {
      const int tn = (t + 1 < t0 + TBS_) ? t + 1 : t;
      const float* po = obs + ((size_t)tn * B_ + b0 + mt * 16 + l15) * IN_;
      ou0a = __builtin_nontemporal_load((const f32x4*)(po + quad * 8));
      ou0b = __builtin_nontemporal_load((const f32x4*)(po + quad * 8 + 4));
      ou1a = __builtin_nontemporal_load((const f32x4*)(po + 32 + quad * 8));
      ou1b = __builtin_nontemporal_load((const f32x4*)(po + 32 + quad * 8 + 4));
    }

    // ============ layer 1 ============
    ar = (f32x4){0.f, 0.f, 0.f, 0.f}; az = ar; ani = ar; anh = ar;
#pragma unroll
    for (int kc = 0; kc < 8; ++kc) {
      bf16x8v ai_ = h0A[kc];                 // h0n[t], unmasked
      bf16x8v am  = rs0 ? z8 : h1A[kc];      // mask*h1[t-1]
      const int o = kc * 32 + quad * 8;
      ar  = MFMA_B16(ai_, *(const bf16x8v*)&iR1[o], ar);
      az  = MFMA_B16(ai_, *(const bf16x8v*)&iZ1[o], az);
      ani = MFMA_B16(ai_, *(const bf16x8v*)&iN1[o], ani);
      ar  = MFMA_B16(am, *(const bf16x8v*)&hR1[o], ar);
      az  = MFMA_B16(am, *(const bf16x8v*)&hZ1[o], az);
      anh = MFMA_B16(am, *(const bf16x8v*)&hN1[o], anh);
    }
    // epilogue 1: publish slice; NO barrier/signal here (folded into next
    // step's rendezvous — drain hides under next step's L0 compute)
    {
      unsigned short* hw = hx1 + ((size_t)team * 2 + (kk & 1)) * (MBT_ * 256);
#pragma unroll
      for (int r = 0; r < 4; ++r) {
        const int m = mt * 16 + quad * 4 + r;
        float rr = sigm(ar[r] + b1r);
        float zz = sigm(az[r] + b1z);
        float nn = tanh_f(ani[r] + b1i + rr * (anh[r] + b1h));
        float hp = rse[r] ? 0.f : h1v[r];
        float hv = (1.f - zz) * nn + zz * hp;
        h1v[r] = hv;
        st2_coh(hw + m * 256 + colg, f2bf(hv));
      }
    }
    // (buffer-overwrite safety under merged protocol: our publishes at step
    //  kk occur after our wait at kk-1/kk, which implies all siblings
    //  completed their reads of the buffer halves being overwritten.)
  }
  // final deferred out store: L1[t0+TBS-1]
  {
    const int tl = t0 + TBS_ - 1;
#pragma unroll
    for (int r = 0; r < 4; ++r) {
      const int m = mt * 16 + quad * 4 + r;
      __builtin_nontemporal_store(h1v[r],
          &out[((size_t)tl * B_ + b0 + m) * HID_ + 256 + colg]);
    }
  }
#undef RVAL
}

extern "C" void kernel_launch(void* const* d_in, const int* in_sizes, int n_in,
                              void* d_out, int out_size, void* d_ws, size_t ws_size,
                              hipStream_t stream) {
  const float* obs    = (const float*)d_in[0];
  const unsigned char* rst = (const unsigned char*)d_in[1];
  const float* h_init = (const float*)d_in[2];
  const float* W_lin  = (const float*)d_in[3];
  const float* b_lin  = (const float*)d_in[4];
  const float* w_ih0  = (const float*)d_in[5];
  const float* w_hh0  = (const float*)d_in[6];
  const float* b_ih0  = (const float*)d_in[7];
  const float* b_hh0  = (const float*)d_in[8];
  const float* w_ih1  = (const float*)d_in[9];
  const float* w_hh1  = (const float*)d_in[10];
  const float* b_ih1  = (const float*)d_in[11];
  const float* b_hh1  = (const float*)d_in[12];

  // workspace carve (re-initialized every launch; ws is re-poisoned by harness)
  char* w = (char*)d_ws;
  unsigned short* wcp   = (unsigned short*)(w);              // 98304 B
  unsigned short* whh0b = (unsigned short*)(w + 98304);      // 393216 B
  unsigned short* wih1b = (unsigned short*)(w + 491520);
  unsigned short* whh1b = (unsigned short*)(w + 884736);
  float*          bcp   = (float*)(w + 1277952);             // 3072 B
  int*            flagp = (int*)(w + 1281024);               // 16 B
  int*            flags = (int*)(w + 1281088);               // 32 teams * 512 B padded flags
  unsigned short* hx0   = (unsigned short*)(w + 1310720);    // 32*2*64*256*2 = 2 MiB
  unsigned short* hx1   = (unsigned short*)(w + 1310720 + 2097152);

  prep_conv<<<1152, 512, 0, stream>>>(w_hh0, w_ih1, w_hh1, rst, whh0b, flagp, flags);
  prep_wc<<<768, 64, 0, stream>>>(W_lin, b_lin, w_ih0, b_ih0, wcp, bcp);
  gru_main<<<256, 512, 0, stream>>>(obs, rst, h_init, wcp, whh0b, wih1b, whh1b,
                                    bcp, b_hh0, b_ih1, b_hh1, flagp,
                                    flags, hx0, hx1, (float*)d_out);
}

// Round 4
// 655.358 us; speedup vs baseline: 1.8048x; 1.0043x over previous
//
#include <hip/hip_runtime.h>

// RecurrentModel: 2-layer GRU stack. Persistent-weight team design.
// 32 teams x 8 blocks. Team = (batch-group of 128) x (time-chunk of 16).
// Block j of a team owns hidden cols [32j,32j+32) of BOTH layers; its weight
// row-slices live in LDS for the whole kernel. Per step, teams exchange
// h-state slices via d_ws buffers + per-team atomic flags.
// R1: per-team flag padding (512B), relaxed spin, s_sleep(2).
// R2: fence-free rendezvous — sc1 per-access coherent exchange, no wbl2/inv.
// R3: SINGLE rendezvous per step (flag1 redundant; h1 drain hides under L0).
// R4: wave-per-m16-tile decomposition — each of 8 waves owns a DISTINCT 16-row
//     tile and computes BOTH col-16 groups (no duplicated A-frag sc1 loads).
//     Block covers 128 batch rows at the same exchange volume; TBS 32->16.
//     Serial steps/team: ~39 -> ~23. Preps merged into one launch.
#define T_    256
#define B_    256
#define IN_   64
#define HID_  512
#define LS_   256
#define G3_   768
#define TBS_  16     // timesteps per team
#define MBT_  128    // batch rows per team
#define WP_   264    // LDS weight row pitch in shorts (528B: 16B-aligned, 2-way-bank free)
#define FSTRIDE_ 128 // ints per team flag region (512 B)

typedef short bf16x8v __attribute__((ext_vector_type(8)));
typedef float f32x4  __attribute__((ext_vector_type(4)));
typedef unsigned long long u64;

#define MFMA_B16(A, B, C) __builtin_amdgcn_mfma_f32_16x16x32_bf16(A, B, C, 0, 0, 0)

__device__ __forceinline__ unsigned short f2bf(float f) {
  union { float f; unsigned u; } v; v.f = f;
  unsigned r = v.u + 0x7fffu + ((v.u >> 16) & 1u);   // RNE
  return (unsigned short)(r >> 16);
}
__device__ __forceinline__ float sigm(float x) { return 1.0f / (1.0f + __expf(-x)); }
__device__ __forceinline__ float tanh_f(float x) {
  x = fminf(fmaxf(x, -15.0f), 15.0f);
  float e = __expf(-2.0f * x);
  return (1.0f - e) / (1.0f + e);
}

// device-coherent (sc1) 2B store: visible at coherence point, no fence needed
__device__ __forceinline__ void st2_coh(unsigned short* p, unsigned short v) {
  __hip_atomic_store(p, v, __ATOMIC_RELAXED, __HIP_MEMORY_SCOPE_AGENT);
}
// device-coherent 16B load assembled from two 8B coherent loads
__device__ __forceinline__ bf16x8v ld16_coh(const unsigned short* p) {
  union { u64 q[2]; bf16x8v v; } u;
  u.q[0] = __hip_atomic_load((const u64*)p,     __ATOMIC_RELAXED, __HIP_MEMORY_SCOPE_AGENT);
  u.q[1] = __hip_atomic_load((const u64*)(p+4), __ATOMIC_RELAXED, __HIP_MEMORY_SCOPE_AGENT);
  return u.v;
}

// ---------------- merged prep: weight conv + reset sniff + flags + W_c ------
__global__ void prep_all(const float* __restrict__ whh0, const float* __restrict__ wih1,
                         const float* __restrict__ whh1, const unsigned char* __restrict__ rst,
                         const float* __restrict__ W_lin, const float* __restrict__ b_lin,
                         const float* __restrict__ w_ih0, const float* __restrict__ b_ih0,
                         unsigned short* __restrict__ dst, unsigned short* __restrict__ wc,
                         float* __restrict__ bc, int* __restrict__ flagp,
                         int* __restrict__ flags) {
  const int bx = blockIdx.x;
  const int tid = threadIdx.x;
  if (bx < 1152) {
    // bf16 conversion of [whh0 | wih1 | whh1]
    const int idx = bx * 512 + tid;
    const int N1 = G3_ * LS_;
    if (idx < 3 * N1) {
      float v;
      if (idx < N1)            v = whh0[idx];
      else if (idx < 2 * N1)   v = wih1[idx - N1];
      else                     v = whh1[idx - 2 * N1];
      dst[idx] = f2bf(v);
    }
    if (bx == 1 && tid < 32) flags[tid * FSTRIDE_] = 0;  // per-team padded f0
    if (bx == 0) {
      __shared__ int f;
      if (tid == 0) f = 0;
      __syncthreads();
      int any = 0;
      for (int i = 0; i < 8; ++i) {
        int off = tid * 8 + i;
        if ((off & 3) && rst[off]) any = 1;
      }
      if (any) atomicOr(&f, 1);
      __syncthreads();
      if (tid == 0) *flagp = f;   // 1 => byte-packed reset
    }
  } else {
    // fused embed W_c = w_ih0 @ W_lin, b_c; one wave per output row n
    const int n = (bx - 1152) * 8 + (tid >> 6);
    const int i = tid & 63;
    const float* wrow = w_ih0 + (size_t)n * HID_;
    float acc = 0.f;
    for (int h = 0; h < HID_; ++h) acc += wrow[h] * W_lin[h * IN_ + i];
    wc[n * IN_ + i] = f2bf(acc);
    float pb = 0.f;
    for (int h = i; h < HID_; h += 64) pb += wrow[h] * b_lin[h];
#pragma unroll
    for (int off = 32; off > 0; off >>= 1) pb += __shfl_down(pb, off);
    if (i == 0) bc[n] = pb + b_ih0[n];
  }
}

// ---------------- main: persistent-weight recurrent kernel ------------------
__global__ __launch_bounds__(512, 2) void gru_main(
    const float* __restrict__ obs, const unsigned char* __restrict__ rst,
    const float* __restrict__ h_init,
    const unsigned short* __restrict__ wc,     // [768][64] bf16 (global, L2-hot)
    const unsigned short* __restrict__ whh0g,  // [768][256] bf16
    const unsigned short* __restrict__ wih1g, const unsigned short* __restrict__ whh1g,
    const float* __restrict__ bcp, const float* __restrict__ bhh0,
    const float* __restrict__ bih1, const float* __restrict__ bhh1,
    const int* __restrict__ flagp, int* __restrict__ flag0,
    unsigned short* __restrict__ hx0, unsigned short* __restrict__ hx1,
    float* __restrict__ out) {

  // Weight slices, persistent all-kernel: [whh0 | wih1 | whh1], 96 rows x 264 pitch
  __shared__ __align__(16) unsigned short wlds[3 * 96 * WP_];   // 152064 B
  __shared__ int s_sm[128];
  __shared__ int s_start_sh;

  const int tid  = threadIdx.x;
  const int lane = tid & 63;
  const int w    = tid >> 6;            // wave = m16 row-tile 0..7 (128 rows)
  const int l15  = lane & 15;
  const int quad = lane >> 4;

  // block -> (team, slice j); bx&7 ~ XCD heuristic (correctness-independent)
  const int x  = blockIdx.x;
  const int cx = x & 7, m8 = x >> 3;
  const int j  = m8 & 7;                // col-slice 0..7
  const int team = cx * 4 + (m8 >> 3);  // 0..31 (4 teams per XCD)
  const int bg = team & 1, tc = team >> 1;
  const int b0 = bg * MBT_, t0 = tc * TBS_;

  // per-team private flag word (512-B stride kills cross-team line contention)
  int* f0 = flag0 + team * FSTRIDE_;

  const int flag = *flagp;
#define RVAL(i) (rst[flag ? (i) : ((i) << 2)] != 0)

  // ---- stage weight slices into LDS (once) ----
#pragma unroll
  for (int q = 0; q < 3; ++q) {
    const unsigned short* src = (q == 0) ? whh0g : (q == 1) ? wih1g : whh1g;
    for (int cid = tid; cid < 96 * 32; cid += 512) {      // 16B chunks
      int lr = cid >> 5, off8 = (cid & 31) * 8;           // row, short-offset
      int g = lr >> 5, cc = lr & 31;
      int grow = (g << 8) + (j << 5) + cc;                // g*256 + j*32 + cc
      *(f32x4*)&wlds[(q * 96 + lr) * WP_ + off8] =
          *(const f32x4*)&src[(size_t)grow * 256 + off8];
    }
  }

  // ---- per-lane biases, both col-16 groups of the 32-col slice ----
  float b0r[2], b0z[2], b0i[2], b0h[2], b1r[2], b1z[2], b1i[2], b1h[2];
#pragma unroll
  for (int cg = 0; cg < 2; ++cg) {
    const int c = j * 32 + cg * 16 + l15;
    b0r[cg] = bcp[c] + bhh0[c];
    b0z[cg] = bcp[256 + c] + bhh0[256 + c];
    b0i[cg] = bcp[512 + c];
    b0h[cg] = bhh0[512 + c];
    b1r[cg] = bih1[c] + bhh1[c];
    b1z[cg] = bih1[256 + c] + bhh1[256 + c];
    b1i[cg] = bih1[512 + c];
    b1h[cg] = bhh1[512 + c];
  }

  // ---- team-uniform safe start (last reset <= t0 across the 128 batch rows) ----
  if (tid < 128) {
    int s = 0;
    for (int tt = t0; tt >= 1; --tt) {
      if (RVAL(tt * B_ + b0 + tid)) { s = tt; break; }
    }
    s_sm[tid] = s;
  }
  __syncthreads();
  if (tid == 0) {
    int s = s_sm[0];
    for (int k = 1; k < 128; ++k) s = s < s_sm[k] ? s : s_sm[k];
    s_start_sh = s;
  }
  __syncthreads();
  const int s_start = s_start_sh;   // identical across the 8 sibling blocks

  // ---- init A-fragments (rows w*16+l15) and fp32 carries ----
  bf16x8v h0A[8], h1A[8];
  const bf16x8v z8 = {0, 0, 0, 0, 0, 0, 0, 0};
#pragma unroll
  for (int kc = 0; kc < 8; ++kc) { h0A[kc] = z8; h1A[kc] = z8; }
  float h0v[2][4] = {{0.f}}, h1v[2][4] = {{0.f}};
#pragma unroll
  for (int cg = 0; cg < 2; ++cg)
#pragma unroll
    for (int r = 0; r < 4; ++r) { h0v[cg][r] = 0.f; h1v[cg][r] = 0.f; }
  if (s_start == 0) {
    const float* hrow = h_init + (size_t)(b0 + w * 16 + l15) * HID_;
#pragma unroll
    for (int kc = 0; kc < 8; ++kc) {
      f32x4 u0 = *(const f32x4*)(hrow + kc * 32 + quad * 8);
      f32x4 u1 = *(const f32x4*)(hrow + kc * 32 + quad * 8 + 4);
      f32x4 v0 = *(const f32x4*)(hrow + 256 + kc * 32 + quad * 8);
      f32x4 v1 = *(const f32x4*)(hrow + 256 + kc * 32 + quad * 8 + 4);
      bf16x8v a, b;
#pragma unroll
      for (int e = 0; e < 4; ++e) {
        a[e] = (short)f2bf(u0[e]); a[4 + e] = (short)f2bf(u1[e]);
        b[e] = (short)f2bf(v0[e]); b[4 + e] = (short)f2bf(v1[e]);
      }
      h0A[kc] = a; h1A[kc] = b;
    }
#pragma unroll
    for (int cg = 0; cg < 2; ++cg)
#pragma unroll
      for (int r = 0; r < 4; ++r) {
        const int m = w * 16 + quad * 4 + r;
        const int c = j * 32 + cg * 16 + l15;
        h0v[cg][r] = h_init[(size_t)(b0 + m) * HID_ + c];
        h1v[cg][r] = h_init[(size_t)(b0 + m) * HID_ + 256 + c];
      }
  }

  // weight row pointers at cg=0 (cg=1 = +16*WP_ shorts, folded into offset)
  const unsigned short* wR0 = &wlds[(0 * 96 + 0 * 32 + l15) * WP_];
  const unsigned short* wZ0 = &wlds[(0 * 96 + 1 * 32 + l15) * WP_];
  const unsigned short* wN0 = &wlds[(0 * 96 + 2 * 32 + l15) * WP_];
  const unsigned short* iR1 = &wlds[(1 * 96 + 0 * 32 + l15) * WP_];
  const unsigned short* iZ1 = &wlds[(1 * 96 + 1 * 32 + l15) * WP_];
  const unsigned short* iN1 = &wlds[(1 * 96 + 2 * 32 + l15) * WP_];
  const unsigned short* hR1 = &wlds[(2 * 96 + 0 * 32 + l15) * WP_];
  const unsigned short* hZ1 = &wlds[(2 * 96 + 1 * 32 + l15) * WP_];
  const unsigned short* hN1 = &wlds[(2 * 96 + 2 * 32 + l15) * WP_];
#define CGO_ (16 * WP_)

  // obs software pipeline: raw f32x4 regs for the CURRENT step, prefetched
  f32x4 ou0a, ou0b, ou1a, ou1b;
  {
    const float* po = obs + ((size_t)s_start * B_ + b0 + w * 16 + l15) * IN_;
    ou0a = __builtin_nontemporal_load((const f32x4*)(po + quad * 8));
    ou0b = __builtin_nontemporal_load((const f32x4*)(po + quad * 8 + 4));
    ou1a = __builtin_nontemporal_load((const f32x4*)(po + 32 + quad * 8));
    ou1b = __builtin_nontemporal_load((const f32x4*)(po + 32 + quad * 8 + 4));
  }

  for (int t = s_start; t < t0 + TBS_; ++t) {
    const int  kk = t - s_start + 1;          // 1-based team step counter
    const bool wr = (t >= t0);
    const bool rs0 = RVAL(t * B_ + b0 + w * 16 + l15);   // A-row mask
    bool rse[4];
#pragma unroll
    for (int r = 0; r < 4; ++r) rse[r] = RVAL(t * B_ + b0 + w * 16 + quad * 4 + r);

    // ============ layer 0 ============
    f32x4 ar[2], az[2], ani[2], anh[2];
#pragma unroll
    for (int cg = 0; cg < 2; ++cg) {
      ar[cg] = (f32x4){0.f, 0.f, 0.f, 0.f};
      az[cg] = ar[cg]; ani[cg] = ar[cg]; anh[cg] = ar[cg];
    }
    // input side: obs @ W_c^T (K=64), obs raw regs prefetched last iter
    {
#pragma unroll
      for (int kc = 0; kc < 2; ++kc) {
        f32x4 u0 = kc ? ou1a : ou0a;
        f32x4 u1 = kc ? ou1b : ou0b;
        bf16x8v oA;
#pragma unroll
        for (int e = 0; e < 4; ++e) { oA[e] = (short)f2bf(u0[e]); oA[4 + e] = (short)f2bf(u1[e]); }
#pragma unroll
        for (int cg = 0; cg < 2; ++cg) {
          const size_t wo = (size_t)(j * 32 + cg * 16 + l15) * 64 + kc * 32 + quad * 8;
          bf16x8v br = *(const bf16x8v*)&wc[wo];
          bf16x8v bz = *(const bf16x8v*)&wc[wo + (size_t)256 * 64];
          bf16x8v bn = *(const bf16x8v*)&wc[wo + (size_t)512 * 64];
          ar[cg]  = MFMA_B16(oA, br, ar[cg]);
          az[cg]  = MFMA_B16(oA, bz, az[cg]);
          ani[cg] = MFMA_B16(oA, bn, ani[cg]);
        }
      }
    }
    // h side: (mask*h0[t-1]) @ whh0^T (K=256, LDS weights)
#pragma unroll
    for (int kc = 0; kc < 8; ++kc) {
      bf16x8v am = rs0 ? z8 : h0A[kc];
      const int o = kc * 32 + quad * 8;
#pragma unroll
      for (int cg = 0; cg < 2; ++cg) {
        ar[cg]  = MFMA_B16(am, *(const bf16x8v*)&wR0[o + cg * CGO_], ar[cg]);
        az[cg]  = MFMA_B16(am, *(const bf16x8v*)&wZ0[o + cg * CGO_], az[cg]);
        anh[cg] = MFMA_B16(am, *(const bf16x8v*)&wN0[o + cg * CGO_], anh[cg]);
      }
    }
    // epilogue 0: fp32 carry, publish slice (coherent 2B stores). out deferred.
    {
      unsigned short* hw = hx0 + ((size_t)team * 2 + (kk & 1)) * (MBT_ * 256);
#pragma unroll
      for (int cg = 0; cg < 2; ++cg)
#pragma unroll
        for (int r = 0; r < 4; ++r) {
          const int m = w * 16 + quad * 4 + r;
          float rr = sigm(ar[cg][r] + b0r[cg]);
          float zz = sigm(az[cg][r] + b0z[cg]);
          float nn = tanh_f(ani[cg][r] + b0i[cg] + rr * (anh[cg][r] + b0h[cg]));
          float hp = rse[r] ? 0.f : h0v[cg][r];
          float hv = (1.f - zz) * nn + zz * hp;
          h0v[cg][r] = hv;
          st2_coh(hw + m * 256 + j * 32 + cg * 16 + l15, f2bf(hv));
        }
    }
    // ---- SINGLE rendezvous: the barrier's vmcnt(0) drain covers h0[kk]
    // stores AND last iter's h1[kk-1] stores (hidden under L0 compute).
    // f0>=8kk therefore implies: all siblings published h0[kk] and h1[kk-1].
    __syncthreads();
    if (tid == 0) {
      __hip_atomic_fetch_add(f0, 1, __ATOMIC_RELAXED, __HIP_MEMORY_SCOPE_AGENT);
      int cap = 0;
      while (__hip_atomic_load(f0, __ATOMIC_RELAXED, __HIP_MEMORY_SCOPE_AGENT)
                 < 8 * kk && cap < (1 << 16)) { __builtin_amdgcn_s_sleep(2); ++cap; }
      // no acquire fence: reader loads below are per-access coherent (sc1)
    }
    __syncthreads();
    // A-frag refresh FIRST (heads the VMEM queue; L1 MFMA waits on these):
    // h0n[t] (fresh) and h1n[t-1] — coherent loads, rows distinct per wave
    {
      const unsigned short* hr0 =
          hx0 + ((size_t)team * 2 + (kk & 1)) * (MBT_ * 256) + (w * 16 + l15) * 256;
#pragma unroll
      for (int kc = 0; kc < 8; ++kc)
        h0A[kc] = ld16_coh(hr0 + kc * 32 + quad * 8);
      if (kk >= 2) {
        const unsigned short* hr1 =
            hx1 + ((size_t)team * 2 + ((kk - 1) & 1)) * (MBT_ * 256) + (w * 16 + l15) * 256;
#pragma unroll
        for (int kc = 0; kc < 8; ++kc)
          h1A[kc] = ld16_coh(hr1 + kc * 32 + quad * 8);
      }
    }
    // deferred out stores (off the rendezvous path): L0[t] and L1[t-1]
    if (wr) {
#pragma unroll
      for (int cg = 0; cg < 2; ++cg)
#pragma unroll
        for (int r = 0; r < 4; ++r) {
          const int m = w * 16 + quad * 4 + r;
          __builtin_nontemporal_store(h0v[cg][r],
              &out[((size_t)t * B_ + b0 + m) * HID_ + j * 32 + cg * 16 + l15]);
        }
    }
    if (t - 1 >= t0) {
#pragma unroll
      for (int cg = 0; cg < 2; ++cg)
#pragma unroll
        for (int r = 0; r < 4; ++r) {
          const int m = w * 16 + quad * 4 + r;
          __builtin_nontemporal_store(h1v[cg][r],
              &out[((size_t)(t - 1) * B_ + b0 + m) * HID_ + 256 + j * 32 + cg * 16 + l15]);
        }
    }
    // prefetch obs for step t+1
    {
      const int tn = (t + 1 < t0 + TBS_) ? t + 1 : t;
      const float* po = obs + ((size_t)tn * B_ + b0 + w * 16 + l15) * IN_;
      ou0a = __builtin_nontemporal_load((const f32x4*)(po + quad * 8));
      ou0b = __builtin_nontemporal_load((const f32x4*)(po + quad * 8 + 4));
      ou1a = __builtin_nontemporal_load((const f32x4*)(po + 32 + quad * 8));
      ou1b = __builtin_nontemporal_load((const f32x4*)(po + 32 + quad * 8 + 4));
    }

    // ============ layer 1 ============
#pragma unroll
    for (int cg = 0; cg < 2; ++cg) {
      ar[cg] = (f32x4){0.f, 0.f, 0.f, 0.f};
      az[cg] = ar[cg]; ani[cg] = ar[cg]; anh[cg] = ar[cg];
    }
#pragma unroll
    for (int kc = 0; kc < 8; ++kc) {
      bf16x8v ai_ = h0A[kc];                 // h0n[t], unmasked
      bf16x8v am  = rs0 ? z8 : h1A[kc];      // mask*h1[t-1]
      const int o = kc * 32 + quad * 8;
#pragma unroll
      for (int cg = 0; cg < 2; ++cg) {
        ar[cg]  = MFMA_B16(ai_, *(const bf16x8v*)&iR1[o + cg * CGO_], ar[cg]);
        az[cg]  = MFMA_B16(ai_, *(const bf16x8v*)&iZ1[o + cg * CGO_], az[cg]);
        ani[cg] = MFMA_B16(ai_, *(const bf16x8v*)&iN1[o + cg * CGO_], ani[cg]);
        ar[cg]  = MFMA_B16(am, *(const bf16x8v*)&hR1[o + cg * CGO_], ar[cg]);
        az[cg]  = MFMA_B16(am, *(const bf16x8v*)&hZ1[o + cg * CGO_], az[cg]);
        anh[cg] = MFMA_B16(am, *(const bf16x8v*)&hN1[o + cg * CGO_], anh[cg]);
      }
    }
    // epilogue 1: publish slice; NO barrier/signal here (folded into next
    // step's rendezvous — drain hides under next step's L0 compute)
    {
      unsigned short* hw = hx1 + ((size_t)team * 2 + (kk & 1)) * (MBT_ * 256);
#pragma unroll
      for (int cg = 0; cg < 2; ++cg)
#pragma unroll
        for (int r = 0; r < 4; ++r) {
          const int m = w * 16 + quad * 4 + r;
          float rr = sigm(ar[cg][r] + b1r[cg]);
          float zz = sigm(az[cg][r] + b1z[cg]);
          float nn = tanh_f(ani[cg][r] + b1i[cg] + rr * (anh[cg][r] + b1h[cg]));
          float hp = rse[r] ? 0.f : h1v[cg][r];
          float hv = (1.f - zz) * nn + zz * hp;
          h1v[cg][r] = hv;
          st2_coh(hw + m * 256 + j * 32 + cg * 16 + l15, f2bf(hv));
        }
    }
    // (buffer-overwrite safety under merged protocol: our publishes at step
    //  kk occur after our wait at kk, which implies all siblings completed
    //  their reads of the buffer halves being overwritten.)
  }
  // final deferred out store: L1[t0+TBS-1]
  {
    const int tl = t0 + TBS_ - 1;
#pragma unroll
    for (int cg = 0; cg < 2; ++cg)
#pragma unroll
      for (int r = 0; r < 4; ++r) {
        const int m = w * 16 + quad * 4 + r;
        __builtin_nontemporal_store(h1v[cg][r],
            &out[((size_t)tl * B_ + b0 + m) * HID_ + 256 + j * 32 + cg * 16 + l15]);
      }
  }
#undef RVAL
#undef CGO_
}

extern "C" void kernel_launch(void* const* d_in, const int* in_sizes, int n_in,
                              void* d_out, int out_size, void* d_ws, size_t ws_size,
                              hipStream_t stream) {
  const float* obs    = (const float*)d_in[0];
  const unsigned char* rst = (const unsigned char*)d_in[1];
  const float* h_init = (const float*)d_in[2];
  const float* W_lin  = (const float*)d_in[3];
  const float* b_lin  = (const float*)d_in[4];
  const float* w_ih0  = (const float*)d_in[5];
  const float* w_hh0  = (const float*)d_in[6];
  const float* b_ih0  = (const float*)d_in[7];
  const float* b_hh0  = (const float*)d_in[8];
  const float* w_ih1  = (const float*)d_in[9];
  const float* w_hh1  = (const float*)d_in[10];
  const float* b_ih1  = (const float*)d_in[11];
  const float* b_hh1  = (const float*)d_in[12];

  // workspace carve (re-initialized every launch; ws is re-poisoned by harness)
  char* w = (char*)d_ws;
  unsigned short* wcp   = (unsigned short*)(w);              // 98304 B
  unsigned short* whh0b = (unsigned short*)(w + 98304);      // 393216 B
  unsigned short* wih1b = (unsigned short*)(w + 491520);
  unsigned short* whh1b = (unsigned short*)(w + 884736);
  float*          bcp   = (float*)(w + 1277952);             // 3072 B
  int*            flagp = (int*)(w + 1281024);               // 16 B
  int*            flags = (int*)(w + 1281088);               // 32 teams * 512 B padded flags
  unsigned short* hx0   = (unsigned short*)(w + 1310720);    // 32*2*128*256*2 = 4 MiB
  unsigned short* hx1   = (unsigned short*)(w + 1310720 + 4194304);
  // total ws usage: 1310720 + 8 MiB ≈ 9.7 MB

  prep_all<<<1152 + 96, 512, 0, stream>>>(w_hh0, w_ih1, w_hh1, rst,
                                          W_lin, b_lin, w_ih0, b_ih0,
                                          whh0b, wcp, bcp, flagp, flags);
  gru_main<<<256, 512, 0, stream>>>(obs, rst, h_init, wcp, whh0b, wih1b, whh1b,
                                    bcp, b_hh0, b_ih1, b_hh1, flagp,
                                    flags, hx0, hx1, (float*)d_out);
}